// Round 2
// baseline (113.188 us; speedup 1.0000x reference)
//
#include <hip/hip_runtime.h>
#include <math.h>

#define SRf 48000.0f
#define CSOUND 343.0f
#define RIR_LEN 24000
#define TAPS 81
#define HALFT 40
#define NB 8
#define NM 21                  // per-axis entries with order <= 10
#define NTRIP (NM * NM * NM)   // 9261 candidate triples
#define NKEPT 1561             // triples with total order <= 10 (analytic count)
#define TILE 750
#define NTILES (RIR_LEN / TILE)  // 32
#define BLOCK 256

// 0.9^q for q = 0..10
__device__ __constant__ float c_beta[11] = {
    1.0f, 0.9f, 0.81f, 0.729f, 0.6561f, 0.59049f, 0.531441f,
    0.4782969f, 0.43046721f, 0.387420489f, 0.3486784401f};

// Per-axis image table restricted to order <= 10:
//   m in [0,10]:  p=0, n=m-5  -> sign=+1, off=2n, order=2|n|
//   m in [11,20]: p=1, n=m-15 -> sign=-1, off=2n, order=|n-1|+|n|
__device__ __forceinline__ void axis_entry(int m, float& sgn, float& off, int& ord) {
    if (m < 11) {
        int n = m - 5;
        sgn = 1.0f;
        off = 2.0f * (float)n;
        ord = 2 * abs(n);
    } else {
        int n = m - 15;
        sgn = -1.0f;
        off = 2.0f * (float)n;
        ord = abs(n - 1) + abs(n);
    }
}

__global__ __launch_bounds__(BLOCK) void rir_kernel(const float* __restrict__ x,
                                                    float* __restrict__ out) {
    __shared__ float s_tile[TILE];
    __shared__ float s_amp[NKEPT];
    __shared__ float s_frac[NKEPT];
    __shared__ float s_spf[NKEPT];
    __shared__ int s_i0[NKEPT];
    __shared__ int s_cnt;

    const float PIF = 3.14159265358979323846f;
    const int wg = blockIdx.x;
    const int b = wg >> 5;           // / NTILES
    const int tile = wg & (NTILES - 1);
    const int t0 = tile * TILE;
    const int tid = threadIdx.x;

    // room / mic / src (uniform across block -> scalar loads)
    const float* xb = x + b * 9;
    const float r0 = xb[0] * 10.0f, r1 = xb[1] * 10.0f, r2 = xb[2] * 10.0f;
    const float m0 = xb[3] * r0, m1 = xb[4] * r1, m2 = xb[5] * r2;
    const float s0 = xb[6] * r0, s1 = xb[7] * r1, s2 = xb[8] * r2;

    if (tid == 0) s_cnt = 0;
    for (int j = tid; j < TILE; j += BLOCK) s_tile[j] = 0.0f;
    __syncthreads();

    if (tile == 0 && tid == 0) {
        float d0 = m0 - s0, d1 = m1 - s1, d2 = m2 - s2;
        float dist = sqrtf(d0 * d0 + d1 * d1 + d2 * d2);
        out[NB * RIR_LEN + b] = 40.0f + SRf * dist / CSOUND;
    }

    // ---- phase A: evaluate all candidate triples, compact tile-intersecting images
    for (int i = tid; i < NTRIP; i += BLOCK) {
        int mi = i / (NM * NM);
        int rem = i - mi * (NM * NM);
        int mj = rem / NM;
        int mk = rem - mj * NM;

        float si, oi_; int qi; axis_entry(mi, si, oi_, qi);
        float sj, oj_; int qj; axis_entry(mj, sj, oj_, qj);
        float sk, ok_; int qk; axis_entry(mk, sk, ok_, qk);
        int q = qi + qj + qk;
        if (q > 10) continue;

        float dx = si * s0 + oi_ * r0 - m0;
        float dy = sj * s1 + oj_ * r1 - m1;
        float dz = sk * s2 + ok_ * r2 - m2;
        float dist = sqrtf(dx * dx + dy * dy + dz * dz);

        float tau = SRf * dist / CSOUND;
        float i0f = floorf(tau);
        int i0 = (int)i0f;

        // tap indices span [i0+40, i0+120]; does that intersect [t0, t0+TILE)?
        if (i0 + (HALFT + TAPS - 1) < t0 || i0 + HALFT >= t0 + TILE) continue;

        float frac = tau - i0f;
        int slot = atomicAdd(&s_cnt, 1);
        s_amp[slot] = c_beta[q] / (4.0f * PIF * dist);
        s_frac[slot] = frac;
        s_spf[slot] = sinf(PIF * frac);
        s_i0[slot] = i0;
    }
    __syncthreads();

    // ---- phase B: flattened (image, tap) work-items, LDS accumulation
    const int n = s_cnt;
    const int total = n * TAPS;
    for (int w = tid; w < total; w += BLOCK) {
        int img = w / TAPS;              // constant division -> magic multiply
        int ki = w - img * TAPS;
        int idx = s_i0[img] + HALFT + ki;
        if (idx < t0 || idx >= t0 + TILE) continue;

        float frac = s_frac[img];
        float tt = (float)(ki - HALFT) - frac;
        if (fabsf(tt) > (float)HALFT) continue;

        float win = 0.5f * (1.0f + cosf(PIF * tt * (1.0f / 41.0f)));
        float spf = s_spf[img];
        float snc = (tt == 0.0f) ? 1.0f : (((ki & 1) ? spf : -spf) / (PIF * tt));
        atomicAdd(&s_tile[idx - t0], s_amp[img] * snc * win);
    }
    __syncthreads();

    // ---- phase C: coalesced tile writeout (tiles are disjoint, cover everything)
    for (int j = tid; j < TILE; j += BLOCK) out[b * RIR_LEN + t0 + j] = s_tile[j];
}

extern "C" void kernel_launch(void* const* d_in, const int* in_sizes, int n_in,
                              void* d_out, int out_size, void* d_ws, size_t ws_size,
                              hipStream_t stream) {
    const float* x = (const float*)d_in[0];
    float* out = (float*)d_out;
    rir_kernel<<<NB * NTILES, BLOCK, 0, stream>>>(x, out);
}

// Round 3
// 50.846 us; speedup vs baseline: 2.2261x; 2.2261x over previous
//
#include <hip/hip_runtime.h>
#include <math.h>

#define SRf 48000.0f
#define CSOUND 343.0f
#define RIR_LEN 24000
#define TAPS 81
#define HALFT 40
#define NB 8
#define NM 21                 // per-axis entries with order <= 10
#define NTRIP (NM * NM * NM)  // 9261 candidate triples
#define TILE 125
#define NT (RIR_LEN / TILE)   // 192 tiles per batch
#define BLOCK 256
#define NMAXIMG 1024          // per-tile image list capacity

// 0.9^q for q = 0..10
__device__ __constant__ float c_beta[11] = {
    1.0f, 0.9f, 0.81f, 0.729f, 0.6561f, 0.59049f, 0.531441f,
    0.4782969f, 0.43046721f, 0.387420489f, 0.3486784401f};

// Per-axis image table restricted to order <= 10:
//   m in [0,10]:  p=0, n=m-5  -> sign=+1, off=2n, order=2|n|
//   m in [11,20]: p=1, n=m-15 -> sign=-1, off=2n, order=|n-1|+|n|
__device__ __forceinline__ void axis_entry(int m, float& sgn, float& off, int& ord) {
    if (m < 11) {
        int n = m - 5;
        sgn = 1.0f;
        off = 2.0f * (float)n;
        ord = 2 * abs(n);
    } else {
        int n = m - 15;
        sgn = -1.0f;
        off = 2.0f * (float)n;
        ord = abs(n - 1) + abs(n);
    }
}

// decode candidate r for batch params; false if order > 10
__device__ __forceinline__ bool img_params(int r, float r0, float r1, float r2,
                                           float m0, float m1, float m2,
                                           float s0, float s1, float s2,
                                           float& amp, float& tau) {
    const float PIF = 3.14159265358979323846f;
    int mi = r / (NM * NM);
    int rem = r - mi * (NM * NM);
    int mj = rem / NM;
    int mk = rem - mj * NM;

    float si, oi_; int qi; axis_entry(mi, si, oi_, qi);
    float sj, oj_; int qj; axis_entry(mj, sj, oj_, qj);
    float sk, ok_; int qk; axis_entry(mk, sk, ok_, qk);
    int q = qi + qj + qk;
    if (q > 10) return false;

    float dx = si * s0 + oi_ * r0 - m0;
    float dy = sj * s1 + oj_ * r1 - m1;
    float dz = sk * s2 + ok_ * r2 - m2;
    float dist = sqrtf(dx * dx + dy * dy + dz * dz);

    amp = c_beta[q] / (4.0f * PIF * dist);
    tau = SRf * dist / CSOUND;
    return true;
}

// kernel 1: evaluate each candidate once; append index to per-(batch,tile) buckets
__global__ __launch_bounds__(BLOCK) void k_scan(const float* __restrict__ x,
                                                float* __restrict__ out,
                                                int* __restrict__ cnt,
                                                unsigned short* __restrict__ lists,
                                                int cap) {
    int t = blockIdx.x * BLOCK + threadIdx.x;

    if (t < NB) {  // fold the 8 origin outputs in
        const float* xb = x + t * 9;
        float r0 = xb[0] * 10.0f, r1 = xb[1] * 10.0f, r2 = xb[2] * 10.0f;
        float d0 = (xb[3] - xb[6]) * r0;
        float d1 = (xb[4] - xb[7]) * r1;
        float d2 = (xb[5] - xb[8]) * r2;
        float dist = sqrtf(d0 * d0 + d1 * d1 + d2 * d2);
        out[NB * RIR_LEN + t] = 40.0f + SRf * dist / CSOUND;
    }

    if (t >= NB * NTRIP) return;
    int b = t / NTRIP;
    int r = t - b * NTRIP;

    const float* xb = x + b * 9;
    float r0 = xb[0] * 10.0f, r1 = xb[1] * 10.0f, r2 = xb[2] * 10.0f;
    float m0 = xb[3] * r0, m1 = xb[4] * r1, m2 = xb[5] * r2;
    float s0 = xb[6] * r0, s1 = xb[7] * r1, s2 = xb[8] * r2;

    float amp, tau;
    if (!img_params(r, r0, r1, r2, m0, m1, m2, s0, s1, s2, amp, tau)) return;

    int i0 = (int)floorf(tau);
    int lo = i0 + HALFT;
    int hi = i0 + HALFT + TAPS - 1;
    if (lo >= RIR_LEN) return;  // entirely past the RIR
    int ta = lo / TILE;
    int tb = min(hi, RIR_LEN - 1) / TILE;

    for (int tl = ta; tl <= tb; ++tl) {
        int bucket = b * NT + tl;
        int slot = atomicAdd(&cnt[bucket], 1);
        if (slot < cap) lists[(size_t)bucket * cap + slot] = (unsigned short)r;
    }
}

// kernel 2: one block per (batch, tile); LDS accumulate its bucket's images
__global__ __launch_bounds__(BLOCK) void k_accum(const float* __restrict__ x,
                                                 float* __restrict__ out,
                                                 const int* __restrict__ cnt,
                                                 const unsigned short* __restrict__ lists,
                                                 int cap) {
    __shared__ float s_tile[TILE];
    __shared__ float s_amp[NMAXIMG];
    __shared__ float s_frac[NMAXIMG];
    __shared__ float s_spf[NMAXIMG];
    __shared__ int s_i0[NMAXIMG];

    const float PIF = 3.14159265358979323846f;
    const int wg = blockIdx.x;
    const int b = wg / NT;
    const int tile = wg - b * NT;
    const int t0 = tile * TILE;
    const int tid = threadIdx.x;

    const float* xb = x + b * 9;
    const float r0 = xb[0] * 10.0f, r1 = xb[1] * 10.0f, r2 = xb[2] * 10.0f;
    const float m0 = xb[3] * r0, m1 = xb[4] * r1, m2 = xb[5] * r2;
    const float s0 = xb[6] * r0, s1 = xb[7] * r1, s2 = xb[8] * r2;

    for (int j = tid; j < TILE; j += BLOCK) s_tile[j] = 0.0f;

    int n = cnt[wg];
    n = min(n, min(cap, NMAXIMG));

    // phase A: per-image params into LDS (each image decoded once)
    for (int i = tid; i < n; i += BLOCK) {
        int r = lists[(size_t)wg * cap + i];
        float amp, tau;
        img_params(r, r0, r1, r2, m0, m1, m2, s0, s1, s2, amp, tau);
        float i0f = floorf(tau);
        float fr = tau - i0f;
        s_amp[i] = amp;
        s_frac[i] = fr;
        s_spf[i] = __sinf(PIF * fr);
        s_i0[i] = (int)i0f;
    }
    __syncthreads();

    // phase B: flattened (image, tap) items
    int total = n * TAPS;
    for (int w = tid; w < total; w += BLOCK) {
        int img = w / TAPS;
        int ki = w - img * TAPS;
        int idx = s_i0[img] + HALFT + ki;
        if (idx < t0 || idx >= t0 + TILE) continue;

        float fr = s_frac[img];
        float tt = (float)(ki - HALFT) - fr;
        if (fabsf(tt) > (float)HALFT) continue;

        float win = 0.5f * (1.0f + __cosf(PIF * tt * (1.0f / 41.0f)));
        float spf = s_spf[img];
        float snc = (tt == 0.0f) ? 1.0f : (((ki & 1) ? spf : -spf) / (PIF * tt));
        atomicAdd(&s_tile[idx - t0], s_amp[img] * snc * win);
    }
    __syncthreads();

    // phase C: coalesced disjoint writeout
    for (int j = tid; j < TILE; j += BLOCK) out[b * RIR_LEN + t0 + j] = s_tile[j];
}

extern "C" void kernel_launch(void* const* d_in, const int* in_sizes, int n_in,
                              void* d_out, int out_size, void* d_ws, size_t ws_size,
                              hipStream_t stream) {
    const float* x = (const float*)d_in[0];
    float* out = (float*)d_out;

    const size_t cnt_bytes = (size_t)NB * NT * sizeof(int);  // 6 KB
    int* cnt = (int*)d_ws;
    unsigned short* lists = (unsigned short*)((char*)d_ws + cnt_bytes);
    size_t avail_u16 = ws_size > cnt_bytes ? (ws_size - cnt_bytes) / 2 : 0;
    int cap = (int)min((size_t)NMAXIMG, avail_u16 / (size_t)(NB * NT));

    hipMemsetAsync(d_ws, 0, cnt_bytes, stream);
    k_scan<<<(NB * NTRIP + BLOCK - 1) / BLOCK, BLOCK, 0, stream>>>(x, out, cnt, lists, cap);
    k_accum<<<NB * NT, BLOCK, 0, stream>>>(x, out, cnt, lists, cap);
}

// Round 4
// 43.923 us; speedup vs baseline: 2.5769x; 1.1576x over previous
//
#include <hip/hip_runtime.h>
#include <math.h>

#define SRf 48000.0f
#define CSOUND 343.0f
#define RIR_LEN 24000
#define TAPS 81
#define HALFT 40
#define NB 8
#define NM 21                 // per-axis entries with order <= 10
#define TILE 125
#define NT (RIR_LEN / TILE)   // 192 tiles per batch
#define BLOCK 256
#define MAXIMG 1561           // exact count of kept images per batch (upper bound per tile)

// 0.9^q for q = 0..10
__device__ __constant__ float c_beta[11] = {
    1.0f, 0.9f, 0.81f, 0.729f, 0.6561f, 0.59049f, 0.531441f,
    0.4782969f, 0.43046721f, 0.387420489f, 0.3486784401f};

// Per-axis image table restricted to order <= 10:
//   m in [0,10]:  p=0, n=m-5  -> sign=+1, off=2n, order=2|n|
//   m in [11,20]: p=1, n=m-15 -> sign=-1, off=2n, order=|n-1|+|n|
__device__ __forceinline__ void axis_entry(int m, float& sgn, float& off, int& ord) {
    if (m < 11) {
        int n = m - 5;
        sgn = 1.0f;
        off = 2.0f * (float)n;
        ord = 2 * abs(n);
    } else {
        int n = m - 15;
        sgn = -1.0f;
        off = 2.0f * (float)n;
        ord = abs(n - 1) + abs(n);
    }
}

__global__ __launch_bounds__(BLOCK) void rir_kernel(const float* __restrict__ x,
                                                    float* __restrict__ out) {
    __shared__ float s_tile[TILE];
    __shared__ float s_d2[3][NM];   // per-axis squared coordinate delta
    __shared__ int s_q[3][NM];      // per-axis wall-hit order
    __shared__ float s_amp[MAXIMG];
    __shared__ float s_frac[MAXIMG];
    __shared__ float s_spf[MAXIMG];
    __shared__ int s_i0[MAXIMG];
    __shared__ int s_cnt;

    const float PIF = 3.14159265358979323846f;
    const int wg = blockIdx.x;
    const int b = wg / NT;
    const int tile = wg - b * NT;
    const int t0 = tile * TILE;
    const int tid = threadIdx.x;

    const float* xb = x + b * 9;
    const float r0 = xb[0] * 10.0f, r1 = xb[1] * 10.0f, r2 = xb[2] * 10.0f;
    const float m0 = xb[3] * r0, m1 = xb[4] * r1, m2 = xb[5] * r2;
    const float s0 = xb[6] * r0, s1 = xb[7] * r1, s2 = xb[8] * r2;

    if (tid == 0) s_cnt = 0;
    for (int j = tid; j < TILE; j += BLOCK) s_tile[j] = 0.0f;

    if (tid < 3 * NM) {
        int ax = tid / NM;
        int m = tid - ax * NM;
        float rr = (ax == 0) ? r0 : (ax == 1) ? r1 : r2;
        float mm = (ax == 0) ? m0 : (ax == 1) ? m1 : m2;
        float ss = (ax == 0) ? s0 : (ax == 1) ? s1 : s2;
        float sgn, off;
        int q;
        axis_entry(m, sgn, off, q);
        float d = sgn * ss + off * rr - mm;
        s_d2[ax][m] = d * d;
        s_q[ax][m] = q;
    }

    if (tile == 0 && tid == 0) {  // fold the 8 origin outputs in
        float d0 = m0 - s0, d1 = m1 - s1, d2 = m2 - s2;
        float dist = sqrtf(d0 * d0 + d1 * d1 + d2 * d2);
        out[NB * RIR_LEN + b] = 40.0f + SRf * dist / CSOUND;
    }
    __syncthreads();

    // ---- phase A: scan 21^3 candidates with (i,j)-hoisting; compact tile-hitters
    for (int ij = tid; ij < NM * NM; ij += BLOCK) {
        int i = ij / NM;
        int j = ij - i * NM;
        int qij = s_q[0][i] + s_q[1][j];
        if (qij > 10) continue;
        float dxy = s_d2[0][i] + s_d2[1][j];
        for (int k = 0; k < NM; ++k) {
            int q = qij + s_q[2][k];
            if (q > 10) continue;
            float dist = sqrtf(dxy + s_d2[2][k]);
            float tau = SRf * dist / CSOUND;
            float i0f = floorf(tau);
            int i0 = (int)i0f;
            // window sample range [i0+40, i0+120]; intersect [t0, t0+TILE)?
            if (i0 < t0 - (HALFT + TAPS - 1) || i0 >= t0 + TILE - HALFT) continue;
            float fr = tau - i0f;
            int slot = atomicAdd(&s_cnt, 1);
            s_amp[slot] = c_beta[q] / (4.0f * PIF * dist);
            s_frac[slot] = fr;
            s_spf[slot] = __sinf(PIF * fr);
            s_i0[slot] = i0;
        }
    }
    __syncthreads();

    // ---- phase B: flattened (image, tap) work-items, LDS accumulation
    const int n = s_cnt;
    const int total = n * TAPS;
    for (int w = tid; w < total; w += BLOCK) {
        int img = w / TAPS;
        int ki = w - img * TAPS;
        int idx = s_i0[img] + HALFT + ki;
        if (idx < t0 || idx >= t0 + TILE) continue;

        float fr = s_frac[img];
        float tt = (float)(ki - HALFT) - fr;
        if (fabsf(tt) > (float)HALFT) continue;

        float win = 0.5f * (1.0f + __cosf(PIF * tt * (1.0f / 41.0f)));
        float spf = s_spf[img];
        float snc = (tt == 0.0f) ? 1.0f : (((ki & 1) ? spf : -spf) / (PIF * tt));
        atomicAdd(&s_tile[idx - t0], s_amp[img] * snc * win);
    }
    __syncthreads();

    // ---- phase C: disjoint coalesced writeout (covers every output element)
    for (int j = tid; j < TILE; j += BLOCK) out[b * RIR_LEN + t0 + j] = s_tile[j];
}

extern "C" void kernel_launch(void* const* d_in, const int* in_sizes, int n_in,
                              void* d_out, int out_size, void* d_ws, size_t ws_size,
                              hipStream_t stream) {
    const float* x = (const float*)d_in[0];
    float* out = (float*)d_out;
    rir_kernel<<<NB * NT, BLOCK, 0, stream>>>(x, out);
}